// Round 9
// baseline (334.585 us; speedup 1.0000x reference)
//
#include <hip/hip_runtime.h>
#include <cstdint>
#include <cstddef>

// ---------------------------------------------------------------------------
// Transformer block on MI355X (gfx950), bf16 MFMA path.
// R9: proj & fc2 single-pass (no split-K) via BN=64 GEMM tiles (512 blocks,
//     16 MFMA/barrier = m97 ratio) with fused bias+residual fp32 epilogue.
//     Kills ~96 MB of split-K partial traffic + the reduce_add dispatch.
// ---------------------------------------------------------------------------

typedef unsigned short u16;
typedef short bf16x8 __attribute__((ext_vector_type(8)));
typedef float f32x4 __attribute__((ext_vector_type(4)));

#define C_EMBD 1024
#define T_SEQ  2048
#define N_BATCH 2
#define N_HEADS 16
#define HEAD_D 64
#define M_TOK  4096   // N_BATCH * T_SEQ
#define Q_SCALE 0.18033688011112042f  // 1/sqrt(64) * log2(e)

__device__ __forceinline__ u16 f2b(float f) {
  union { float f; unsigned u; } v; v.f = f;
  unsigned r = (v.u + 0x7fffu + ((v.u >> 16) & 1u)) >> 16;  // RNE
  return (u16)r;
}
__device__ __forceinline__ float b2f(u16 u) {
  union { unsigned u; float f; } v; v.u = ((unsigned)u) << 16;
  return v.f;
}
// pack 2 fp32 -> bf16x2 by truncation: lo16 = a.hi16, hi16 = b.hi16 (1 VALU op)
__device__ __forceinline__ unsigned pk2(float a, float b) {
  union { float f; unsigned u; } x, y; x.f = a; y.f = b;
  return __builtin_amdgcn_perm(y.u, x.u, 0x07060302u);
}
__device__ __forceinline__ void load_lds16(const void* g, void* l) {
  __builtin_amdgcn_global_load_lds(
      (const __attribute__((address_space(1))) void*)g,
      (__attribute__((address_space(3))) void*)l, 16, 0, 0);
}
// tanh-form GELU in exp2 domain: x * t/(t+1), t = exp2(2.3021859*(x+0.044715x^3))
__device__ __forceinline__ float gelu_fast(float x) {
  const float p = x * __builtin_fmaf(0.044715f * x, x, 1.0f);
  const float t = __builtin_amdgcn_exp2f(2.3021859215f * p);
  return x * t * __builtin_amdgcn_rcpf(t + 1.0f);
}

// ---------------------------------------------------------------------------
// Fused weight transpose + cast for all 4 weights: W[K][N] fp32 -> Wt[N][K] bf16
// ---------------------------------------------------------------------------
__global__ __launch_bounds__(256) void transpose_cast_all(
    const float* __restrict__ W0, u16* __restrict__ D0,   // attn 1024x3072
    const float* __restrict__ W1, u16* __restrict__ D1,   // proj 1024x1024
    const float* __restrict__ W2, u16* __restrict__ D2,   // fc   1024x4096
    const float* __restrict__ W3, u16* __restrict__ D3) { // fc2  4096x1024
  int id = blockIdx.x;
  const float* W; u16* D; int K, N, t;
  if (id < 3072)      { W = W0; D = D0; K = 1024; N = 3072; t = id; }
  else if (id < 4096) { W = W1; D = D1; K = 1024; N = 1024; t = id - 3072; }
  else if (id < 8192) { W = W2; D = D2; K = 1024; N = 4096; t = id - 4096; }
  else                { W = W3; D = D3; K = 4096; N = 1024; t = id - 8192; }
  const int nTN = N >> 5;
  const int n0 = (t % nTN) * 32, k0 = (t / nTN) * 32;
  __shared__ float tile[32][33];
  const int tx = threadIdx.x & 31, ty = threadIdx.x >> 5;  // ty in [0,8)
#pragma unroll
  for (int i = 0; i < 32; i += 8)
    tile[ty + i][tx] = W[(size_t)(k0 + ty + i) * N + n0 + tx];
  __syncthreads();
#pragma unroll
  for (int i = 0; i < 32; i += 8)
    D[(size_t)(n0 + ty + i) * K + k0 + tx] = f2b(tile[tx][ty + i]);
}

// ---------------------------------------------------------------------------
// LayerNorm over rows of 1024 fp32 -> bf16 out. One block (256 thr) per row.
// ---------------------------------------------------------------------------
__global__ __launch_bounds__(256) void ln_cast(
    const float* __restrict__ X, const float* __restrict__ g,
    const float* __restrict__ b, u16* __restrict__ Y) {
  const int row = blockIdx.x;
  const int tid = threadIdx.x;
  const float4 v = ((const float4*)(X + (size_t)row * C_EMBD))[tid];
  float s = v.x + v.y + v.z + v.w;
  float ss = v.x * v.x + v.y * v.y + v.z * v.z + v.w * v.w;
#pragma unroll
  for (int off = 32; off > 0; off >>= 1) {
    s += __shfl_down(s, off, 64);
    ss += __shfl_down(ss, off, 64);
  }
  __shared__ float red[8];
  __shared__ float stats[2];
  const int wave = tid >> 6, lane = tid & 63;
  if (lane == 0) { red[wave] = s; red[4 + wave] = ss; }
  __syncthreads();
  if (tid == 0) {
    float S = red[0] + red[1] + red[2] + red[3];
    float SS = red[4] + red[5] + red[6] + red[7];
    float mu = S * (1.0f / C_EMBD);
    float var = SS * (1.0f / C_EMBD) - mu * mu;
    stats[0] = mu;
    stats[1] = rsqrtf(var + 1e-5f);
  }
  __syncthreads();
  const float mu = stats[0], rs = stats[1];
  const float4 gv = ((const float4*)g)[tid];
  const float4 bv = ((const float4*)b)[tid];
  ushort4 o;
  o.x = f2b((v.x - mu) * rs * gv.x + bv.x);
  o.y = f2b((v.y - mu) * rs * gv.y + bv.y);
  o.z = f2b((v.z - mu) * rs * gv.z + bv.z);
  o.w = f2b((v.w - mu) * rs * gv.w + bv.w);
  ((ushort4*)(Y + (size_t)row * C_EMBD))[tid] = o;
}

// ---------------------------------------------------------------------------
// GEMM: C[M,N] = A[M,K](bf16) * Bt[N,K](bf16)^T (+epilogue). BK=64,
// xor-swizzled LDS, transposed acc (C^T). Tile 128M x BN N, 4 waves (2x2).
// XCD-aware map (requires M-tiles == 32): XCD j = id%8 owns M-slab [4j,4j+4),
// walks N — A slice resident in its private L2, B shared via L3.
// EPI_RES_F32: fp32 out = acc + bias + res (fused residual, no split-K).
// ---------------------------------------------------------------------------
enum { EPI_BF16 = 0, EPI_RES_F32 = 1, EPI_GELU_BF16 = 2, EPI_QKV = 4 };

template <int EPI, int BN>
__global__ __launch_bounds__(256) void gemm_bt(
    const u16* __restrict__ A, const u16* __restrict__ Bt,
    const float* __restrict__ bias, const float* __restrict__ res,
    void* __restrict__ Cout, void* __restrict__ Cout2, void* __restrict__ Cout3,
    int M, int N, int K) {
  constexpr int TB = BN / 32;            // b-frags per wave
  __shared__ u16 As[128 * 64];
  __shared__ u16 Bs[BN * 64];
  const int tid = threadIdx.x;
  const int wave = tid >> 6, lane = tid & 63;
  const int quad = lane >> 4, l16 = lane & 15;
  const int sw = l16 & 7;

  // XCD-aware swizzle (bijective; id%8 -> XCD round-robin heuristic)
  const int id = (int)blockIdx.y * (int)gridDim.x + (int)blockIdx.x;
  const int mt = ((id & 7) << 2) + ((id >> 3) & 3);
  const int nt_ = id >> 5;
  const int m0 = mt * 128, n0 = nt_ * BN;

  const int wm = (wave >> 1) * 64, wn = (wave & 1) * (BN / 2);

  f32x4 acc[4][TB] = {};  // acc[tm][tn][r]: m = wm+tm*16+l16, n = wn+tn*16+quad*4+r

  // loop-invariant staging geometry
  size_t aOff[4], bOff[TB];
  int aLds[4], bLds[TB];
#pragma unroll
  for (int i = 0; i < 4; ++i) {
    const int c = tid + i * 256;
    const int row = c >> 3, gc = ((c & 7) ^ (row & 7)) * 8;
    aOff[i] = (size_t)(m0 + row) * K + gc;
    aLds[i] = c * 8;
  }
#pragma unroll
  for (int i = 0; i < TB; ++i) {
    const int c = tid + i * 256;
    const int row = c >> 3, gc = ((c & 7) ^ (row & 7)) * 8;
    bOff[i] = (size_t)(n0 + row) * K + gc;
    bLds[i] = c * 8;
  }

  const int kTiles = K >> 6;
  for (int kt = 0; kt < kTiles; ++kt) {
    const int k0 = kt << 6;
#pragma unroll
    for (int i = 0; i < 4; ++i)
      load_lds16(A + aOff[i] + k0, &As[aLds[i]]);
#pragma unroll
    for (int i = 0; i < TB; ++i)
      load_lds16(Bt + bOff[i] + k0, &Bs[bLds[i]]);
    __syncthreads();
#pragma unroll
    for (int ks = 0; ks < 2; ++ks) {
      bf16x8 aF[4], bF[TB];
#pragma unroll
      for (int t = 0; t < 4; ++t)
        aF[t] = *(const bf16x8*)
            &As[(wm + t * 16 + l16) * 64 + (((ks * 4 + quad) ^ sw) * 8)];
#pragma unroll
      for (int t = 0; t < TB; ++t)
        bF[t] = *(const bf16x8*)
            &Bs[(wn + t * 16 + l16) * 64 + (((ks * 4 + quad) ^ sw) * 8)];
#pragma unroll
      for (int tm = 0; tm < 4; ++tm)
#pragma unroll
        for (int tn = 0; tn < TB; ++tn)
          acc[tm][tn] = __builtin_amdgcn_mfma_f32_16x16x32_bf16(
              bF[tn], aF[tm], acc[tm][tn], 0, 0, 0);  // transposed: C^T
    }
    __syncthreads();
  }

#pragma unroll
  for (int tm = 0; tm < 4; ++tm) {
    const int row = m0 + wm + tm * 16 + l16;
#pragma unroll
    for (int tn = 0; tn < TB; ++tn) {
      const int col = n0 + wn + tn * 16 + quad * 4;
      if constexpr (EPI == EPI_RES_F32) {
        const float4 bz = *(const float4*)&bias[col];
        const float4 rz = *(const float4*)&res[(size_t)row * N + col];
        float4 o;
        o.x = acc[tm][tn][0] + bz.x + rz.x;
        o.y = acc[tm][tn][1] + bz.y + rz.y;
        o.z = acc[tm][tn][2] + bz.z + rz.z;
        o.w = acc[tm][tn][3] + bz.w + rz.w;
        *(float4*)&((float*)Cout)[(size_t)row * N + col] = o;
      } else if constexpr (EPI == EPI_QKV) {
        // row = token; col in [0,3072): [0,1024)=Q, [1024,2048)=K, rest=V
        const int bb = row >> 11, t = row & (T_SEQ - 1);
        const float4 bz = *(const float4*)&bias[col];
        float v0 = acc[tm][tn][0] + bz.x, v1 = acc[tm][tn][1] + bz.y;
        float v2 = acc[tm][tn][2] + bz.z, v3 = acc[tm][tn][3] + bz.w;
        const int sec = col >> 10;           // wave-uniform (16-col group)
        const int h = (col & 1023) >> 6, d4 = col & 63;
        const int bh = bb * N_HEADS + h;
        if (sec == 0) {                      // Q, pre-scaled
          ushort4 o;
          o.x = f2b(v0 * Q_SCALE); o.y = f2b(v1 * Q_SCALE);
          o.z = f2b(v2 * Q_SCALE); o.w = f2b(v3 * Q_SCALE);
          *(ushort4*)&((u16*)Cout)[((size_t)bh * T_SEQ + t) * HEAD_D + d4] = o;
        } else if (sec == 1) {               // K
          ushort4 o;
          o.x = f2b(v0); o.y = f2b(v1); o.z = f2b(v2); o.w = f2b(v3);
          *(ushort4*)&((u16*)Cout2)[((size_t)bh * T_SEQ + t) * HEAD_D + d4] = o;
        } else {                             // V^T: [bh][d][t]
          u16* vp = (u16*)Cout3 + ((size_t)bh * HEAD_D + d4) * T_SEQ + t;
          vp[0] = f2b(v0); vp[T_SEQ] = f2b(v1);
          vp[2 * T_SEQ] = f2b(v2); vp[3 * T_SEQ] = f2b(v3);
        }
      } else {
        const float4 bz = *(const float4*)&bias[col];
        float v0 = acc[tm][tn][0] + bz.x, v1 = acc[tm][tn][1] + bz.y;
        float v2 = acc[tm][tn][2] + bz.z, v3 = acc[tm][tn][3] + bz.w;
        if constexpr (EPI == EPI_GELU_BF16) {
          v0 = gelu_fast(v0); v1 = gelu_fast(v1);
          v2 = gelu_fast(v2); v3 = gelu_fast(v3);
        }
        ushort4 o;
        o.x = f2b(v0); o.y = f2b(v1); o.z = f2b(v2); o.w = f2b(v3);
        *(ushort4*)&((u16*)Cout)[(size_t)row * N + col] = o;
      }
    }
  }
}

// ---------------------------------------------------------------------------
// Flash attention (causal), LDS-staged double-buffered K/V, triangle-paired.
// XCD-aware map: XCD j = id%8 serves heads {j, j+8, j+16, j+24} — K/V
// footprint 2 MB resident in its private L2. Transposed math throughout.
// ---------------------------------------------------------------------------
__global__ __launch_bounds__(256) void attn_fwd(
    const u16* __restrict__ Q, const u16* __restrict__ Kb,
    const u16* __restrict__ Vt, u16* __restrict__ Y) {
  const int id = (int)blockIdx.y * (int)gridDim.x + (int)blockIdx.x;
  const int bh = (id & 7) + (((id >> 3) & 3) << 3);
  const int pair = id >> 5;
  const int nqt = (int)(T_SEQ / 64);
  const int tid = threadIdx.x;
  const int wave = tid >> 6, lane = tid & 63;
  const int quad = lane >> 4, l16 = lane & 15;
  const int sw = l16 & 7;  // xor-swizzle key for frag reads
  const u16* Qp = Q + (size_t)bh * T_SEQ * HEAD_D;
  const u16* Kp = Kb + (size_t)bh * T_SEQ * HEAD_D;
  const u16* Vp = Vt + (size_t)bh * HEAD_D * T_SEQ;

  __shared__ u16 Ks[2][64 * 64];
  __shared__ u16 Vs[2][64 * 64];
  __shared__ u16 Pl[4][16 * 72];

  // loop-invariant staging geometry (chunk c -> row c>>3, col8 (c&7)^(row&7))
  const int c1 = tid, c2 = tid + 256;
  const int r1 = c1 >> 3, g1 = ((c1 & 7) ^ (r1 & 7)) * 8;
  const int r2 = c2 >> 3, g2 = ((c2 & 7) ^ (r2 & 7)) * 8;
  const size_t kO1 = (size_t)r1 * HEAD_D + g1, kO2 = (size_t)r2 * HEAD_D + g2;
  const size_t vO1 = (size_t)r1 * T_SEQ + g1, vO2 = (size_t)r2 * T_SEQ + g2;
  u16* const dK1[2] = {&Ks[0][c1 * 8], &Ks[1][c1 * 8]};
  u16* const dK2[2] = {&Ks[0][c2 * 8], &Ks[1][c2 * 8]};
  u16* const dV1[2] = {&Vs[0][c1 * 8], &Vs[1][c1 * 8]};
  u16* const dV2[2] = {&Vs[0][c2 * 8], &Vs[1][c2 * 8]};

  auto stageK = [&](int bb, int k0) {
    const u16* base = Kp + (size_t)k0 * HEAD_D;
    load_lds16(base + kO1, dK1[bb]);
    load_lds16(base + kO2, dK2[bb]);
  };
  auto stageV = [&](int bb, int k0) {
    const u16* base = Vp + k0;
    load_lds16(base + vO1, dV1[bb]);
    load_lds16(base + vO2, dV2[bb]);
  };

  const int b = bh >> 4, h = bh & 15;

#pragma unroll 1
  for (int phase = 0; phase < 2; ++phase) {
    const int qb = phase == 0 ? (nqt - 1 - pair) : pair;
    const int q0 = qb * 64;
    const int qglob = q0 + wave * 16 + l16;  // this lane's q row

    if (phase == 1) __syncthreads();  // protect Ks/Vs from prior readers

    bf16x8 qF[2];
    qF[0] = *(const bf16x8*)&Qp[(size_t)qglob * HEAD_D + quad * 8];
    qF[1] = *(const bf16x8*)&Qp[(size_t)qglob * HEAD_D + 32 + quad * 8];

    f32x4 o[4] = {};   // O^T: d = nt*16 + quad*4 + r, q = l16
    float mrun = -3e38f, lrun = 0.0f;

    stageK(0, 0);
    stageV(0, 0);

    int buf = 0;
    for (int kb = 0; kb <= qb; ++kb) {
      const int k0 = kb * 64;
      __syncthreads();  // drains DMA + all waves' prior-buffer reads
      if (kb < qb) {
        stageK(buf ^ 1, k0 + 64);
        stageV(buf ^ 1, k0 + 64);
      }
      // S^T: key = nt*16 + quad*4 + r (rows), q = l16 (cols)
      f32x4 st[4] = {};
#pragma unroll
      for (int ks = 0; ks < 2; ++ks) {
#pragma unroll
        for (int nt = 0; nt < 4; ++nt) {
          bf16x8 kF = *(const bf16x8*)
              &Ks[buf][(nt * 16 + l16) * 64 + (((ks * 4 + quad) ^ sw) * 8)];
          st[nt] = __builtin_amdgcn_mfma_f32_16x16x32_bf16(kF, qF[ks], st[nt],
                                                           0, 0, 0);
        }
      }
      if (kb == qb) {  // causal mask, diagonal tile only
#pragma unroll
        for (int nt = 0; nt < 4; ++nt) {
#pragma unroll
          for (int r = 0; r < 4; ++r) {
            const int key = k0 + nt * 16 + quad * 4 + r;
            if (key > qglob) st[nt][r] = -3e38f;
          }
        }
      }
      // online softmax over keys: register tree + cross-quad (lanes ^16,^32)
      float m = st[0][0];
#pragma unroll
      for (int nt = 0; nt < 4; ++nt)
#pragma unroll
        for (int r = 0; r < 4; ++r) m = fmaxf(m, st[nt][r]);
      m = fmaxf(m, __shfl_xor(m, 16, 64));
      m = fmaxf(m, __shfl_xor(m, 32, 64));
      const float nm = fmaxf(mrun, m);
      const float alpha = __builtin_amdgcn_exp2f(mrun - nm);
      mrun = nm;
      float sum = 0.0f;
#pragma unroll
      for (int nt = 0; nt < 4; ++nt)
#pragma unroll
        for (int r = 0; r < 4; ++r) {
          const float p = __builtin_amdgcn_exp2f(st[nt][r] - nm);
          st[nt][r] = p;
          sum += p;
        }
      sum += __shfl_xor(sum, 16, 64);
      sum += __shfl_xor(sum, 32, 64);
      lrun = lrun * alpha + sum;
#pragma unroll
      for (int nt = 0; nt < 4; ++nt)
#pragma unroll
        for (int r = 0; r < 4; ++r) o[nt][r] *= alpha;
      // P^T -> LDS: row = q (l16), col = key; v_perm truncating pack
#pragma unroll
      for (int nt = 0; nt < 4; ++nt) {
        uint2 pk;
        pk.x = pk2(st[nt][0], st[nt][1]);
        pk.y = pk2(st[nt][2], st[nt][3]);
        *(uint2*)&Pl[wave][l16 * 72 + nt * 16 + quad * 4] = pk;
      }
      // O^T += V^T P^T  (A = V^T from Vs, B = P^T from Pl)
#pragma unroll
      for (int ks = 0; ks < 2; ++ks) {
        bf16x8 aP = *(const bf16x8*)&Pl[wave][l16 * 72 + ks * 32 + quad * 8];
#pragma unroll
        for (int nt = 0; nt < 4; ++nt) {
          bf16x8 vF = *(const bf16x8*)
              &Vs[buf][(nt * 16 + l16) * 64 + (((ks * 4 + quad) ^ sw) * 8)];
          o[nt] =
              __builtin_amdgcn_mfma_f32_16x16x32_bf16(vF, aP, o[nt], 0, 0, 0);
        }
      }
      buf ^= 1;
    }

    // write O^T / l -> Y bf16 [B,T,C]: row = token (l16), cols = d
    const float rl = 1.0f / lrun;
    u16* yp = Y + ((size_t)(b * T_SEQ + qglob)) * C_EMBD + h * HEAD_D;
#pragma unroll
    for (int nt = 0; nt < 4; ++nt) {
      ushort4 ov;
      ov.x = f2b(o[nt][0] * rl); ov.y = f2b(o[nt][1] * rl);
      ov.z = f2b(o[nt][2] * rl); ov.w = f2b(o[nt][3] * rl);
      *(ushort4*)&yp[nt * 16 + quad * 4] = ov;
    }
  }
}

// ---------------------------------------------------------------------------
// Host side
// ---------------------------------------------------------------------------
extern "C" void kernel_launch(void* const* d_in, const int* in_sizes, int n_in,
                              void* d_out, int out_size, void* d_ws,
                              size_t ws_size, hipStream_t stream) {
  const float* x      = (const float*)d_in[0];
  const float* W_attn = (const float*)d_in[1];
  const float* b_attn = (const float*)d_in[2];
  const float* W_proj = (const float*)d_in[3];
  const float* b_proj = (const float*)d_in[4];
  const float* W_fc   = (const float*)d_in[5];
  const float* b_fc   = (const float*)d_in[6];
  const float* W_fc2  = (const float*)d_in[7];
  const float* b_fc2  = (const float*)d_in[8];
  const float* ln1_g  = (const float*)d_in[9];
  const float* ln1_b  = (const float*)d_in[10];
  const float* ln2_g  = (const float*)d_in[11];
  const float* ln2_b  = (const float*)d_in[12];

  u16* wqkvT = (u16*)d_ws;                            // [3072][1024] bf16
  u16* wprojT = wqkvT + (size_t)3072 * 1024;          // [1024][1024]
  u16* wfcT  = wprojT + (size_t)1024 * 1024;          // [4096][1024]
  u16* wfc2T = wfcT + (size_t)4096 * 1024;            // [1024][4096]
  u16* Abuf  = wfc2T + (size_t)1024 * 4096;           // [4096][1024] bf16
  float* x1  = (float*)(Abuf + (size_t)M_TOK * C_EMBD);  // [4096][1024] f32
  u16* hbuf  = (u16*)(x1 + (size_t)M_TOK * C_EMBD);   // [4096][4096] bf16, 32MB
  u16* Qb    = hbuf + (size_t)M_TOK * 4096;           // [32][2048][64]
  u16* Kbuf  = Qb + (size_t)32 * T_SEQ * HEAD_D;
  u16* Vtb   = Kbuf + (size_t)32 * T_SEQ * HEAD_D;

  const dim3 blk(256);

  transpose_cast_all<<<12288, blk, 0, stream>>>(
      W_attn, wqkvT, W_proj, wprojT, W_fc, wfcT, W_fc2, wfc2T);

  ln_cast<<<M_TOK, blk, 0, stream>>>(x, ln1_g, ln1_b, Abuf);

  // qkv GEMM with fused split/reorder/scale epilogue
  gemm_bt<EPI_QKV, 128><<<dim3(3072 / 128, M_TOK / 128), blk, 0, stream>>>(
      Abuf, wqkvT, b_attn, nullptr, Qb, Kbuf, Vtb, M_TOK, 3072, 1024);

  attn_fwd<<<dim3(T_SEQ / 128, 32), blk, 0, stream>>>(Qb, Kbuf, Vtb, Abuf);

  // proj: single pass, fused bias + x residual -> x1 (fp32)
  gemm_bt<EPI_RES_F32, 64><<<dim3(1024 / 64, M_TOK / 128), blk, 0, stream>>>(
      Abuf, wprojT, b_proj, x, x1, nullptr, nullptr, M_TOK, 1024, 1024);

  ln_cast<<<M_TOK, blk, 0, stream>>>(x1, ln2_g, ln2_b, Abuf);

  gemm_bt<EPI_GELU_BF16, 128><<<dim3(4096 / 128, M_TOK / 128), blk, 0, stream>>>(
      Abuf, wfcT, b_fc, nullptr, hbuf, nullptr, nullptr, M_TOK, 4096, 1024);

  // fc2: single pass, K=4096, fused bias + x1 residual -> d_out (fp32)
  gemm_bt<EPI_RES_F32, 64><<<dim3(1024 / 64, M_TOK / 128), blk, 0, stream>>>(
      hbuf, wfc2T, b_fc2, x1, d_out, nullptr, nullptr, M_TOK, 1024, 4096);
}